// Round 2
// baseline (284.156 us; speedup 1.0000x reference)
//
#include <hip/hip_runtime.h>

// Problem constants (from reference): predictions [16,12,512,512] f32,
// targets [16,512,512] int32 (harness: integer -> const int*).
// out = mean over all B*C*H*W of (pred[b,c,h,w] - (c <= t[b,h,w]))^2.

constexpr int BATCH    = 16;
constexpr int NCLS     = 12;
constexpr int HW       = 512 * 512;          // 262144 = 2^18
constexpr int NPIX     = BATCH * HW;         // 4,194,304
constexpr int NGROUPS  = NPIX / 4;           // 1,048,576 float4 groups
constexpr int NBLOCKS  = 2048;
constexpr int NTHREADS = 256;

__global__ __launch_bounds__(NTHREADS) void ord_partial_kernel(
        const float* __restrict__ pred,
        const int*   __restrict__ tgt,
        float*       __restrict__ partial) {
    const int tid      = blockIdx.x * NTHREADS + threadIdx.x;
    const int nthreads = gridDim.x * NTHREADS;

    float acc = 0.0f;

    for (int g = tid; g < NGROUPS; g += nthreads) {
        const int p4 = g << 2;               // first pixel of this group
        const int b  = p4 >> 18;             // p4 / HW (group never straddles a batch)
        const int hw = p4 & (HW - 1);        // p4 % HW

        const int4 t = *reinterpret_cast<const int4*>(tgt + p4);
        const float* base = pred + (size_t)b * (NCLS * HW) + hw;

        #pragma unroll
        for (int c = 0; c < NCLS; ++c) {
            const float4 v = *reinterpret_cast<const float4*>(base + (size_t)c * HW);
            const float d0 = v.x - ((c <= t.x) ? 1.0f : 0.0f);
            const float d1 = v.y - ((c <= t.y) ? 1.0f : 0.0f);
            const float d2 = v.z - ((c <= t.z) ? 1.0f : 0.0f);
            const float d3 = v.w - ((c <= t.w) ? 1.0f : 0.0f);
            acc = fmaf(d0, d0, acc);
            acc = fmaf(d1, d1, acc);
            acc = fmaf(d2, d2, acc);
            acc = fmaf(d3, d3, acc);
        }
    }

    // 64-lane wave reduction
    #pragma unroll
    for (int off = 32; off > 0; off >>= 1)
        acc += __shfl_down(acc, off, 64);

    __shared__ float wsum[NTHREADS / 64];
    const int lane = threadIdx.x & 63;
    const int wid  = threadIdx.x >> 6;
    if (lane == 0) wsum[wid] = acc;
    __syncthreads();
    if (threadIdx.x == 0)
        partial[blockIdx.x] = wsum[0] + wsum[1] + wsum[2] + wsum[3];
}

__global__ __launch_bounds__(NTHREADS) void ord_final_kernel(
        const float* __restrict__ partial,
        float*       __restrict__ out) {
    double acc = 0.0;
    for (int i = threadIdx.x; i < NBLOCKS; i += NTHREADS)
        acc += (double)partial[i];

    #pragma unroll
    for (int off = 32; off > 0; off >>= 1)
        acc += __shfl_down(acc, off, 64);

    __shared__ double wsum[NTHREADS / 64];
    const int lane = threadIdx.x & 63;
    const int wid  = threadIdx.x >> 6;
    if (lane == 0) wsum[wid] = acc;
    __syncthreads();
    if (threadIdx.x == 0) {
        const double total = wsum[0] + wsum[1] + wsum[2] + wsum[3];
        out[0] = (float)(total / (double)((size_t)NPIX * NCLS));
    }
}

extern "C" void kernel_launch(void* const* d_in, const int* in_sizes, int n_in,
                              void* d_out, int out_size, void* d_ws, size_t ws_size,
                              hipStream_t stream) {
    const float* pred = (const float*)d_in[0];
    const int*   tgt  = (const int*)d_in[1];
    float* out        = (float*)d_out;
    float* partial    = (float*)d_ws;        // NBLOCKS floats = 8 KB scratch

    ord_partial_kernel<<<NBLOCKS, NTHREADS, 0, stream>>>(pred, tgt, partial);
    ord_final_kernel<<<1, NTHREADS, 0, stream>>>(partial, out);
}

// Round 5
// 264.651 us; speedup vs baseline: 1.0737x; 1.0737x over previous
//
#include <hip/hip_runtime.h>

// predictions [16,12,512,512] f32, targets [16,512,512] int32.
// out = mean over B*C*H*W of (pred[b,c,h,w] - (c <= t[b,h,w]))^2.

constexpr int BATCH    = 16;
constexpr int NCLS     = 12;
constexpr int HW       = 512 * 512;              // 2^18
constexpr int NPIX     = BATCH * HW;             // 4,194,304
constexpr int NGROUPS  = NPIX / 4;               // 1,048,576 float4 groups
constexpr int NBLOCKS  = 2048;
constexpr int NTHREADS = 256;
constexpr int TOTALTHR = NBLOCKS * NTHREADS;     // 524,288 -> exactly 2 groups/thread

// Native clang vectors — __builtin_nontemporal_load requires these, not
// HIP_vector_type structs (float4/int4).
typedef float v4f __attribute__((ext_vector_type(4)));
typedef int   v4i __attribute__((ext_vector_type(4)));

__device__ __forceinline__ float group_sumsq(const float* __restrict__ pred,
                                             const int*   __restrict__ tgt,
                                             int g) {
    const int p4 = g << 2;                 // first pixel of group
    const int b  = p4 >> 18;               // p4 / HW (group never straddles a batch)
    const int hw = p4 & (HW - 1);          // p4 % HW

    const v4i t = __builtin_nontemporal_load(reinterpret_cast<const v4i*>(tgt + p4));
    const float* base = pred + (size_t)b * (NCLS * HW) + hw;

    float acc = 0.0f;
    #pragma unroll
    for (int c = 0; c < NCLS; ++c) {
        const v4f v = __builtin_nontemporal_load(
            reinterpret_cast<const v4f*>(base + (size_t)c * HW));
        const float d0 = v.x - ((c <= t.x) ? 1.0f : 0.0f);
        const float d1 = v.y - ((c <= t.y) ? 1.0f : 0.0f);
        const float d2 = v.z - ((c <= t.z) ? 1.0f : 0.0f);
        const float d3 = v.w - ((c <= t.w) ? 1.0f : 0.0f);
        acc = fmaf(d0, d0, acc);
        acc = fmaf(d1, d1, acc);
        acc = fmaf(d2, d2, acc);
        acc = fmaf(d3, d3, acc);
    }
    return acc;
}

__global__ __launch_bounds__(NTHREADS) void ord_partial_kernel(
        const float* __restrict__ pred,
        const int*   __restrict__ tgt,
        float*       __restrict__ partial) {
    const int tid = blockIdx.x * NTHREADS + threadIdx.x;

    // Exactly two groups per thread, fully unrolled so all loads can be in flight.
    float acc = group_sumsq(pred, tgt, tid)
              + group_sumsq(pred, tgt, tid + TOTALTHR);

    // 64-lane wave reduction
    #pragma unroll
    for (int off = 32; off > 0; off >>= 1)
        acc += __shfl_down(acc, off, 64);

    __shared__ float wsum[NTHREADS / 64];
    const int lane = threadIdx.x & 63;
    const int wid  = threadIdx.x >> 6;
    if (lane == 0) wsum[wid] = acc;
    __syncthreads();
    if (threadIdx.x == 0)
        partial[blockIdx.x] = wsum[0] + wsum[1] + wsum[2] + wsum[3];
}

__global__ __launch_bounds__(NTHREADS) void ord_final_kernel(
        const float* __restrict__ partial,
        float*       __restrict__ out) {
    double acc = 0.0;
    for (int i = threadIdx.x; i < NBLOCKS; i += NTHREADS)
        acc += (double)partial[i];

    #pragma unroll
    for (int off = 32; off > 0; off >>= 1)
        acc += __shfl_down(acc, off, 64);

    __shared__ double wsum[NTHREADS / 64];
    const int lane = threadIdx.x & 63;
    const int wid  = threadIdx.x >> 6;
    if (lane == 0) wsum[wid] = acc;
    __syncthreads();
    if (threadIdx.x == 0) {
        const double total = wsum[0] + wsum[1] + wsum[2] + wsum[3];
        out[0] = (float)(total / (double)((size_t)NPIX * NCLS));
    }
}

extern "C" void kernel_launch(void* const* d_in, const int* in_sizes, int n_in,
                              void* d_out, int out_size, void* d_ws, size_t ws_size,
                              hipStream_t stream) {
    const float* pred = (const float*)d_in[0];
    const int*   tgt  = (const int*)d_in[1];
    float* out        = (float*)d_out;
    float* partial    = (float*)d_ws;    // 2048 floats = 8 KB of the workspace

    ord_partial_kernel<<<NBLOCKS, NTHREADS, 0, stream>>>(pred, tgt, partial);
    ord_final_kernel<<<1, NTHREADS, 0, stream>>>(partial, out);
}